// Round 2
// baseline (1757.852 us; speedup 1.0000x reference)
//
#include <hip/hip_runtime.h>

#define BB 8
#define NN 256
#define FF 59
#define CC 128
#define EPSV 1e-5f

// ws layout (floats)
#define WS_V     0
#define WS_ASRC  (WS_V + BB*NN*CC)
#define WS_ADST  (WS_ASRC + BB*NN*CC)
#define WS_PWT   (WS_ADST + BB*NN*CC)
#define WS_T1    (WS_PWT + 6*CC)
#define WS_T2    (WS_T1 + CC)
#define WS_WT    (WS_T2 + CC)

// blocks 0..383: projections (type = blk>>7: 0=v/W_lin, 1=a_src/W_src, 2=a_dst/W_dst)
// block  384   : fold BN into pos_w (-> pwt transposed, T1) and attn_w (-> wt transposed, T2)
__global__ __launch_bounds__(256) void prep_kernel(
    const float* __restrict__ x, const float* __restrict__ W_lin,
    const float* __restrict__ W_src, const float* __restrict__ W_dst,
    const float* __restrict__ pos_w, const float* __restrict__ pos_b,
    const float* __restrict__ pos_g, const float* __restrict__ pos_bb,
    const float* __restrict__ pos_m, const float* __restrict__ pos_v,
    const float* __restrict__ attn_w, const float* __restrict__ attn_b,
    const float* __restrict__ attn_g, const float* __restrict__ attn_bb,
    const float* __restrict__ attn_m, const float* __restrict__ attn_v,
    float* __restrict__ ws)
{
    int blk = blockIdx.x;
    int tid = threadIdx.x;
    if (blk < 384) {
        int type = blk >> 7;
        int g    = blk & 127;
        int b    = g >> 4;
        int n0   = (g & 15) * 16;
        const float* W = (type == 0) ? W_lin : (type == 1) ? W_src : W_dst;
        float* outp = ws + ((type == 0) ? WS_V : (type == 1) ? WS_ASRC : WS_ADST);
        __shared__ float Wl[CC * FF];   // 30208 B
        __shared__ float xs[16 * FF];   //  3776 B
        for (int idx = tid; idx < CC * FF; idx += 256) Wl[idx] = W[idx];
        const float* xrow = x + (size_t)(b * NN + n0) * FF;
        for (int idx = tid; idx < 16 * FF; idx += 256) xs[idx] = xrow[idx];
        __syncthreads();
        int c = tid & 127, h = tid >> 7;
        float acc[8];
#pragma unroll
        for (int q = 0; q < 8; ++q) acc[q] = 0.f;
        for (int f = 0; f < FF; ++f) {
            float w = Wl[c * FF + f];
#pragma unroll
            for (int q = 0; q < 8; ++q) acc[q] += w * xs[(h * 8 + q) * FF + f];
        }
#pragma unroll
        for (int q = 0; q < 8; ++q) {
            int n = n0 + h * 8 + q;
            outp[(b * NN + n) * CC + c] = acc[q];
        }
    } else {
        __shared__ float S2s[CC];
        if (tid < CC) {
            int c = tid;
            float S1 = rsqrtf(pos_v[c] + EPSV) * pos_g[c];
            ws[WS_T1 + c] = (pos_b[c] - pos_m[c]) * S1 + pos_bb[c];
#pragma unroll
            for (int k = 0; k < 6; ++k) ws[WS_PWT + k * CC + c] = pos_w[c * 6 + k] * S1;
            float S2 = rsqrtf(attn_v[c] + EPSV) * attn_g[c];
            S2s[c] = S2;
            ws[WS_T2 + c] = (attn_b[c] - attn_m[c]) * S2 + attn_bb[c];
        }
        __syncthreads();
        for (int idx = tid; idx < CC * CC; idx += 256) {
            int d = idx & 127, cc2 = idx >> 7;
            ws[WS_WT + cc2 * CC + d] = attn_w[d * CC + cc2] * S2s[d];
        }
    }
}

// One block per (b, i). Compact valid j's (dist2 <= r^2), then tiles of 16 j:
// phase1: delta/alpha/u -> LDS; phase2: scores matmul with wt column held in
// 128 VGPRs per thread (preloaded once per block; zero global loads in the
// hot loop); phase3: streaming exp-sum (scores in [0,~60], no max needed).
__global__ __launch_bounds__(256, 2) void main_kernel(
    const float* __restrict__ pos, const float* __restrict__ nrm,
    const int* __restrict__ rptr, const float* __restrict__ ws,
    float* __restrict__ out)
{
    const float* v    = ws + WS_V;
    const float* asrc = ws + WS_ASRC;
    const float* adst = ws + WS_ADST;
    const float* pwt  = ws + WS_PWT;
    const float* T1   = ws + WS_T1;
    const float* T2   = ws + WS_T2;
    const float* wt   = ws + WS_WT;

    int blk = blockIdx.x;
    int b = blk >> 8, i = blk & 255;
    int tid = threadIdx.x;

    __shared__ float relf[NN * 6];
    __shared__ int   jlist[NN];
    __shared__ int   wcnt[4];
    __shared__ int   cnt_s;
    __shared__ float alpha_t[CC * 20];   // [c][slot], stride 20 (16B-aligned float4 at +0/+8)
    __shared__ float u_lds[16 * CC];     // [slot][d]
    __shared__ float sered[CC], ored[CC];

    int c    = tid & 127;   // channel lane (c-role in phase1, d-role in phase2)
    int half = tid >> 7;

    // ---- preload wt column c into registers (reused across all tiles) ----
    float wreg[CC];
    {
        const float* wtp = wt + c;
#pragma unroll
        for (int k = 0; k < CC; ++k) wreg[k] = wtp[k * CC];
    }

    int rv = rptr[0];
    float r2 = (float)(rv * rv);
    const float* pib = pos + (size_t)(b * NN + i) * 3;
    const float* nib = nrm + (size_t)(b * NN + i) * 3;
    float pix = pib[0], piy = pib[1], piz = pib[2];
    float nix = nib[0], niy = nib[1], niz = nib[2];
    {
        int j = tid;
        const float* pj = pos + (size_t)(b * NN + j) * 3;
        const float* nj = nrm + (size_t)(b * NN + j) * 3;
        float dx = pix - pj[0], dy = piy - pj[1], dz = piz - pj[2];
        float ex = nix - nj[0], ey = niy - nj[1], ez = niz - nj[2];
        float d2 = dx * dx + dy * dy + dz * dz;
        bool valid = (d2 <= r2);
        unsigned long long m = __ballot(valid);
        int w = tid >> 6, lane = tid & 63;
        if (lane == 0) wcnt[w] = __popcll(m);
        __syncthreads();
        int off = 0;
        for (int w2 = 0; w2 < w; ++w2) off += wcnt[w2];
        if (tid == 0) cnt_s = wcnt[0] + wcnt[1] + wcnt[2] + wcnt[3];
        int rank = __popcll(m & ((1ull << lane) - 1ull));
        if (valid) {
            int s = off + rank;
            jlist[s] = j;
            relf[s * 6 + 0] = dx; relf[s * 6 + 1] = dy; relf[s * 6 + 2] = dz;
            relf[s * 6 + 3] = ex; relf[s * 6 + 4] = ey; relf[s * 6 + 5] = ez;
        }
    }
    __syncthreads();
    int cnt = cnt_s;   // >= 1 (self-loop)

    float pw[6];
#pragma unroll
    for (int k = 0; k < 6; ++k) pw[k] = pwt[k * CC + c];
    float T1c    = T1[c];
    float T2d    = T2[c];
    float adst_c = adst[(b * NN + i) * CC + c];

    float se = 0.f, ov = 0.f;

    for (int base = 0; base < cnt; base += 16) {
        int tcnt = min(16, cnt - base);
        // ---- phase 1: delta/alpha/u for this tile ----
#pragma unroll
        for (int q = 0; q < 8; ++q) {
            int js = half * 8 + q;
            float aval = 0.f, uval = 0.f;
            if (js < tcnt) {
                int j = jlist[base + js];
                const float* rf = &relf[(base + js) * 6];
                float dsum = T1c;
#pragma unroll
                for (int k = 0; k < 6; ++k) dsum += pw[k] * rf[k];
                float delta = fmaxf(dsum, 0.f);
                float as = asrc[(b * NN + j) * CC + c];
                float vv = v[(b * NN + j) * CC + c];
                aval = adst_c - as + delta;
                uval = vv + delta;
            }
            alpha_t[c * 20 + js] = aval;
            u_lds[js * CC + c]   = uval;
        }
        __syncthreads();
        // ---- phase 2: scores = alpha @ wt (+T2), register-resident wt ----
        if (half * 8 < tcnt) {
            float acc[8];
#pragma unroll
            for (int q = 0; q < 8; ++q) acc[q] = T2d;
#pragma unroll
            for (int cc2 = 0; cc2 < CC; ++cc2) {
                float wv = wreg[cc2];
                const float* ap = &alpha_t[cc2 * 20 + half * 8];
                float4 a0 = *(const float4*)ap;
                float4 a1 = *(const float4*)(ap + 4);
                acc[0] += a0.x * wv; acc[1] += a0.y * wv;
                acc[2] += a0.z * wv; acc[3] += a0.w * wv;
                acc[4] += a1.x * wv; acc[5] += a1.y * wv;
                acc[6] += a1.z * wv; acc[7] += a1.w * wv;
            }
            // ---- phase 3: streaming exp-sum ----
#pragma unroll
            for (int q = 0; q < 8; ++q) {
                int js = half * 8 + q;
                if (js < tcnt) {
                    float s = fmaxf(acc[q], 0.f);
                    float e = __expf(s);
                    se += e;
                    ov += e * u_lds[js * CC + c];
                }
            }
        }
        __syncthreads();
    }

    if (half == 1) { sered[c] = se; ored[c] = ov; }
    __syncthreads();
    if (half == 0) {
        float S = se + sered[c];
        float O = ov + ored[c];
        out[(size_t)(b * NN + i) * CC + c] = O / S;
    }
}

extern "C" void kernel_launch(void* const* d_in, const int* in_sizes, int n_in,
                              void* d_out, int out_size, void* d_ws, size_t ws_size,
                              hipStream_t stream) {
    const float* x      = (const float*)d_in[0];
    const float* pos    = (const float*)d_in[1];
    const float* normal = (const float*)d_in[2];
    const float* W_lin  = (const float*)d_in[3];
    const float* W_src  = (const float*)d_in[4];
    const float* W_dst  = (const float*)d_in[5];
    const float* pos_w  = (const float*)d_in[6];
    const float* pos_b  = (const float*)d_in[7];
    const float* pos_g  = (const float*)d_in[8];
    const float* pos_bb = (const float*)d_in[9];
    const float* pos_m  = (const float*)d_in[10];
    const float* pos_v  = (const float*)d_in[11];
    const float* attn_w = (const float*)d_in[12];
    const float* attn_b = (const float*)d_in[13];
    const float* attn_g = (const float*)d_in[14];
    const float* attn_bb= (const float*)d_in[15];
    const float* attn_m = (const float*)d_in[16];
    const float* attn_v = (const float*)d_in[17];
    const int*   rptr   = (const int*)d_in[18];
    float* ws  = (float*)d_ws;
    float* out = (float*)d_out;

    prep_kernel<<<dim3(385), dim3(256), 0, stream>>>(
        x, W_lin, W_src, W_dst, pos_w, pos_b, pos_g, pos_bb, pos_m, pos_v,
        attn_w, attn_b, attn_g, attn_bb, attn_m, attn_v, ws);
    main_kernel<<<dim3(2048), dim3(256), 0, stream>>>(pos, normal, rptr, ws, out);
}

// Round 3
// 131.436 us; speedup vs baseline: 13.3742x; 13.3742x over previous
//
#include <hip/hip_runtime.h>

typedef _Float16 h2 __attribute__((ext_vector_type(2)));
typedef unsigned int uint32;

#define BB 8
#define NN 256
#define FF 59
#define CC 128
#define EPSV 1e-5f

// ws layout (dword offsets)
#define WS_V     0
#define WS_ASRC  (WS_V + BB*NN*CC)
#define WS_ADST  (WS_ASRC + BB*NN*CC)
#define WS_PWT   (WS_ADST + BB*NN*CC)
#define WS_T1    (WS_PWT + 6*CC)
#define WS_T2    (WS_T1 + CC)
#define WS_WTH   (WS_T2 + CC)   // 64*128 dwords: packed half2 (wt[2p][d], wt[2p+1][d])

#if __has_builtin(__builtin_amdgcn_fdot2)
#define FDOT2(a, b, c) __builtin_amdgcn_fdot2((a), (b), (c), false)
#else
static __device__ __forceinline__ float fdot2_emul(h2 a, h2 b, float c) {
    return c + (float)a.x * (float)b.x + (float)a.y * (float)b.y;
}
#define FDOT2 fdot2_emul
#endif

static __device__ __forceinline__ h2 as_h2(uint32 u) {
    return __builtin_bit_cast(h2, u);
}

// blocks 0..383: projections (type = blk>>7: 0=v/W_lin, 1=a_src/W_src, 2=a_dst/W_dst)
// block  384   : fold BN into pos_w (-> pwt, T1) and attn_w (-> packed f16 wth, T2)
__global__ __launch_bounds__(256) void prep_kernel(
    const float* __restrict__ x, const float* __restrict__ W_lin,
    const float* __restrict__ W_src, const float* __restrict__ W_dst,
    const float* __restrict__ pos_w, const float* __restrict__ pos_b,
    const float* __restrict__ pos_g, const float* __restrict__ pos_bb,
    const float* __restrict__ pos_m, const float* __restrict__ pos_v,
    const float* __restrict__ attn_w, const float* __restrict__ attn_b,
    const float* __restrict__ attn_g, const float* __restrict__ attn_bb,
    const float* __restrict__ attn_m, const float* __restrict__ attn_v,
    float* __restrict__ ws)
{
    int blk = blockIdx.x;
    int tid = threadIdx.x;
    if (blk < 384) {
        int type = blk >> 7;
        int g    = blk & 127;
        int b    = g >> 4;
        int n0   = (g & 15) * 16;
        const float* W = (type == 0) ? W_lin : (type == 1) ? W_src : W_dst;
        float* outp = ws + ((type == 0) ? WS_V : (type == 1) ? WS_ASRC : WS_ADST);
        __shared__ float Wl[CC * 60];   // rows padded 59->60 for aligned b128
        __shared__ float xs[16 * 60];
        for (int idx = tid; idx < CC * 60; idx += 256) {
            int r = idx / 60, f = idx - r * 60;
            Wl[idx] = (f < FF) ? W[r * FF + f] : 0.f;
        }
        const float* xrow = x + (size_t)(b * NN + n0) * FF;
        for (int idx = tid; idx < 16 * 60; idx += 256) {
            int r = idx / 60, f = idx - r * 60;
            xs[idx] = (f < FF) ? xrow[r * FF + f] : 0.f;
        }
        __syncthreads();
        int c = tid & 127, h = tid >> 7;
        float acc[8];
#pragma unroll
        for (int q = 0; q < 8; ++q) acc[q] = 0.f;
#pragma unroll 3
        for (int f4 = 0; f4 < 15; ++f4) {
            float4 wq = *(const float4*)&Wl[c * 60 + f4 * 4];
#pragma unroll
            for (int q = 0; q < 8; ++q) {
                float4 xq = *(const float4*)&xs[(h * 8 + q) * 60 + f4 * 4];
                acc[q] = fmaf(wq.x, xq.x, acc[q]);
                acc[q] = fmaf(wq.y, xq.y, acc[q]);
                acc[q] = fmaf(wq.z, xq.z, acc[q]);
                acc[q] = fmaf(wq.w, xq.w, acc[q]);
            }
        }
#pragma unroll
        for (int q = 0; q < 8; ++q) {
            int n = n0 + h * 8 + q;
            outp[(b * NN + n) * CC + c] = acc[q];
        }
    } else {
        __shared__ float S2s[CC];
        if (tid < CC) {
            int c = tid;
            float S1 = rsqrtf(pos_v[c] + EPSV) * pos_g[c];
            ws[WS_T1 + c] = (pos_b[c] - pos_m[c]) * S1 + pos_bb[c];
#pragma unroll
            for (int k = 0; k < 6; ++k) ws[WS_PWT + k * CC + c] = pos_w[c * 6 + k] * S1;
            float S2 = rsqrtf(attn_v[c] + EPSV) * attn_g[c];
            S2s[c] = S2;
            ws[WS_T2 + c] = (attn_b[c] - attn_m[c]) * S2 + attn_bb[c];
        }
        __syncthreads();
        uint32* wthp = (uint32*)ws + WS_WTH;
        for (int idx = tid; idx < 64 * CC; idx += 256) {
            int p = idx & 63, d = idx >> 6;
            float s = S2s[d];
            float2 w2 = *(const float2*)&attn_w[d * CC + 2 * p];
            h2 hv;
            hv.x = (_Float16)(w2.x * s);
            hv.y = (_Float16)(w2.y * s);
            wthp[p * CC + d] = __builtin_bit_cast(uint32, hv);
        }
    }
}

// One block per (b, i). Compact valid j's, then tiles of 16 j:
// phase1: alpha (f16 -> LDS), u (registers); phase2: fdot2 matmul, wt half2
// from global (coalesced, L2-hot); phase3: streaming exp-sum with u in regs.
__global__ __launch_bounds__(256) void main_kernel(
    const float* __restrict__ pos, const float* __restrict__ nrm,
    const int* __restrict__ rptr, const float* __restrict__ ws,
    float* __restrict__ out)
{
    const float* v    = ws + WS_V;
    const float* asrc = ws + WS_ASRC;
    const float* adst = ws + WS_ADST;
    const float* pwt  = ws + WS_PWT;
    const float* T1   = ws + WS_T1;
    const float* T2   = ws + WS_T2;
    const uint32* wth = (const uint32*)ws + WS_WTH;

    int blk = blockIdx.x;
    int b = blk >> 8, i = blk & 255;
    int tid = threadIdx.x;

    __shared__ float relf[NN * 6];
    __shared__ int   jlist[NN];
    __shared__ int   wcnt[4];
    __shared__ int   cnt_s;
    __shared__ _Float16 alpha_h[16 * 136];  // [slot][c], 272 B rows (16B-aligned)
    __shared__ float sered[CC], ored[CC];

    int rv = rptr[0];
    float r2 = (float)(rv * rv);
    const float* pib = pos + (size_t)(b * NN + i) * 3;
    const float* nib = nrm + (size_t)(b * NN + i) * 3;
    float pix = pib[0], piy = pib[1], piz = pib[2];
    float nix = nib[0], niy = nib[1], niz = nib[2];
    {
        int j = tid;
        const float* pj = pos + (size_t)(b * NN + j) * 3;
        const float* nj = nrm + (size_t)(b * NN + j) * 3;
        float dx = pix - pj[0], dy = piy - pj[1], dz = piz - pj[2];
        float ex = nix - nj[0], ey = niy - nj[1], ez = niz - nj[2];
        float d2 = dx * dx + dy * dy + dz * dz;
        bool valid = (d2 <= r2);
        unsigned long long m = __ballot(valid);
        int w = tid >> 6, lane = tid & 63;
        if (lane == 0) wcnt[w] = __popcll(m);
        __syncthreads();
        int off = 0;
        for (int w2 = 0; w2 < w; ++w2) off += wcnt[w2];
        if (tid == 0) cnt_s = wcnt[0] + wcnt[1] + wcnt[2] + wcnt[3];
        int rank = __popcll(m & ((1ull << lane) - 1ull));
        if (valid) {
            int s = off + rank;
            jlist[s] = j;
            relf[s * 6 + 0] = dx; relf[s * 6 + 1] = dy; relf[s * 6 + 2] = dz;
            relf[s * 6 + 3] = ex; relf[s * 6 + 4] = ey; relf[s * 6 + 5] = ez;
        }
    }
    __syncthreads();
    int cnt = cnt_s;   // >= 1 (self-loop)

    int c    = tid & 127;
    int half = tid >> 7;   // wave-uniform

    float pw[6];
#pragma unroll
    for (int k = 0; k < 6; ++k) pw[k] = pwt[k * CC + c];
    float T1c    = T1[c];
    float T2d    = T2[c];
    float adst_c = adst[(b * NN + i) * CC + c];

    float se = 0.f, ov = 0.f;

    for (int base = 0; base < cnt; base += 16) {
        int tcnt = min(16, cnt - base);
        int myn  = tcnt - half * 8;   // how many of my 8 slots are valid
        float u_reg[8];
        // ---- phase 1: alpha -> LDS (f16), u -> registers ----
        {
            const int4* jp = (const int4*)&jlist[base + half * 8];
            int4 ja = jp[0], jb4 = jp[1];
            int jarr[8] = {ja.x, ja.y, ja.z, ja.w, jb4.x, jb4.y, jb4.z, jb4.w};
            const float4* rp = (const float4*)&relf[(base + half * 8) * 6];
            float rf[48];
#pragma unroll
            for (int t = 0; t < 12; ++t) {
                float4 xx = rp[t];
                rf[4 * t + 0] = xx.x; rf[4 * t + 1] = xx.y;
                rf[4 * t + 2] = xx.z; rf[4 * t + 3] = xx.w;
            }
#pragma unroll
            for (int q = 0; q < 8; ++q) {
                float aval = 0.f, uval = 0.f;
                if (q < myn) {
                    int j = jarr[q];
                    float dsum = T1c;
#pragma unroll
                    for (int k = 0; k < 6; ++k) dsum = fmaf(pw[k], rf[q * 6 + k], dsum);
                    float delta = fmaxf(dsum, 0.f);
                    aval = adst_c - asrc[(b * NN + j) * CC + c] + delta;
                    uval = v[(b * NN + j) * CC + c] + delta;
                }
                alpha_h[(half * 8 + q) * 136 + c] = (_Float16)aval;
                u_reg[q] = uval;
            }
        }
        __syncthreads();
        // ---- phase 2: scores = alpha @ wt (+T2) via v_dot2_f32_f16 ----
        if (myn > 0) {
            float acc[8];
#pragma unroll
            for (int q = 0; q < 8; ++q) acc[q] = T2d;
            const uint32* wp = wth + c;
#pragma unroll 4
            for (int co = 0; co < 16; ++co) {
                uint32 w0 = wp[(co * 4 + 0) * CC];
                uint32 w1 = wp[(co * 4 + 1) * CC];
                uint32 w2 = wp[(co * 4 + 2) * CC];
                uint32 w3 = wp[(co * 4 + 3) * CC];
                h2 h0 = as_h2(w0), h1 = as_h2(w1), hh2 = as_h2(w2), h3 = as_h2(w3);
#pragma unroll
                for (int q = 0; q < 8; ++q) {
                    uint4 av = *(const uint4*)&alpha_h[(half * 8 + q) * 136 + co * 8];
                    acc[q] = FDOT2(as_h2(av.x), h0, acc[q]);
                    acc[q] = FDOT2(as_h2(av.y), h1, acc[q]);
                    acc[q] = FDOT2(as_h2(av.z), hh2, acc[q]);
                    acc[q] = FDOT2(as_h2(av.w), h3, acc[q]);
                }
            }
            // ---- phase 3: streaming exp-sum (scores>=0, no max needed) ----
#pragma unroll
            for (int q = 0; q < 8; ++q) {
                if (q < myn) {
                    float s = fmaxf(acc[q], 0.f);
                    float e = __expf(s);
                    se += e;
                    ov += e * u_reg[q];
                }
            }
        }
        __syncthreads();
    }

    if (half == 1) { sered[c] = se; ored[c] = ov; }
    __syncthreads();
    if (half == 0) {
        float S = se + sered[c];
        float O = ov + ored[c];
        out[(size_t)(b * NN + i) * CC + c] = O / S;
    }
}

extern "C" void kernel_launch(void* const* d_in, const int* in_sizes, int n_in,
                              void* d_out, int out_size, void* d_ws, size_t ws_size,
                              hipStream_t stream) {
    const float* x      = (const float*)d_in[0];
    const float* pos    = (const float*)d_in[1];
    const float* normal = (const float*)d_in[2];
    const float* W_lin  = (const float*)d_in[3];
    const float* W_src  = (const float*)d_in[4];
    const float* W_dst  = (const float*)d_in[5];
    const float* pos_w  = (const float*)d_in[6];
    const float* pos_b  = (const float*)d_in[7];
    const float* pos_g  = (const float*)d_in[8];
    const float* pos_bb = (const float*)d_in[9];
    const float* pos_m  = (const float*)d_in[10];
    const float* pos_v  = (const float*)d_in[11];
    const float* attn_w = (const float*)d_in[12];
    const float* attn_b = (const float*)d_in[13];
    const float* attn_g = (const float*)d_in[14];
    const float* attn_bb= (const float*)d_in[15];
    const float* attn_m = (const float*)d_in[16];
    const float* attn_v = (const float*)d_in[17];
    const int*   rptr   = (const int*)d_in[18];
    float* ws  = (float*)d_ws;
    float* out = (float*)d_out;

    prep_kernel<<<dim3(385), dim3(256), 0, stream>>>(
        x, W_lin, W_src, W_dst, pos_w, pos_b, pos_g, pos_bb, pos_m, pos_v,
        attn_w, attn_b, attn_g, attn_bb, attn_m, attn_v, ws);
    main_kernel<<<dim3(2048), dim3(256), 0, stream>>>(pos, normal, rptr, ws, out);
}

// Round 4
// 130.609 us; speedup vs baseline: 13.4589x; 1.0063x over previous
//
#include <hip/hip_runtime.h>

typedef _Float16 h2 __attribute__((ext_vector_type(2)));
typedef unsigned int uint32;

#define BB 8
#define NN 256
#define FF 59
#define CC 128
#define EPSV 1e-5f

// ws layout (dword offsets)
#define WS_V     0
#define WS_ASRC  (WS_V + BB*NN*CC)
#define WS_ADST  (WS_ASRC + BB*NN*CC)
#define WS_PWT   (WS_ADST + BB*NN*CC)
#define WS_T1    (WS_PWT + 6*CC)
#define WS_T2    (WS_T1 + CC)
#define WS_WTH   (WS_T2 + CC)   // 64*128 dwords: packed half2 (wt[2p][d], wt[2p+1][d])

#if __has_builtin(__builtin_amdgcn_fdot2)
#define FDOT2(a, b, c) __builtin_amdgcn_fdot2((a), (b), (c), false)
#else
static __device__ __forceinline__ float fdot2_emul(h2 a, h2 b, float c) {
    return c + (float)a.x * (float)b.x + (float)a.y * (float)b.y;
}
#define FDOT2 fdot2_emul
#endif

static __device__ __forceinline__ h2 as_h2(uint32 u) {
    return __builtin_bit_cast(h2, u);
}

// blocks 0..767: projections, 8 n-rows each (type = blk>>8: 0=v, 1=a_src, 2=a_dst)
// block  768   : fold BN into pos_w (-> pwt, T1) and attn_w (-> packed f16 wth, T2)
__global__ __launch_bounds__(256) void prep_kernel(
    const float* __restrict__ x, const float* __restrict__ W_lin,
    const float* __restrict__ W_src, const float* __restrict__ W_dst,
    const float* __restrict__ pos_w, const float* __restrict__ pos_b,
    const float* __restrict__ pos_g, const float* __restrict__ pos_bb,
    const float* __restrict__ pos_m, const float* __restrict__ pos_v,
    const float* __restrict__ attn_w, const float* __restrict__ attn_b,
    const float* __restrict__ attn_g, const float* __restrict__ attn_bb,
    const float* __restrict__ attn_m, const float* __restrict__ attn_v,
    float* __restrict__ ws)
{
    int blk = blockIdx.x;
    int tid = threadIdx.x;
    if (blk < 768) {
        int type = blk >> 8;
        int g    = blk & 255;
        int b    = g >> 5;
        int n0   = (g & 31) * 8;
        const float* W = (type == 0) ? W_lin : (type == 1) ? W_src : W_dst;
        float* outp = ws + ((type == 0) ? WS_V : (type == 1) ? WS_ASRC : WS_ADST);
        __shared__ float Wl[CC * 60];   // rows padded 59->60 for aligned b128
        __shared__ float xs[8 * 60];
        for (int idx = tid; idx < CC * 60; idx += 256) {
            int r = idx / 60, f = idx - r * 60;
            Wl[idx] = (f < FF) ? W[r * FF + f] : 0.f;
        }
        const float* xrow = x + (size_t)(b * NN + n0) * FF;
        for (int idx = tid; idx < 8 * 60; idx += 256) {
            int r = idx / 60, f = idx - r * 60;
            xs[idx] = (f < FF) ? xrow[r * FF + f] : 0.f;
        }
        __syncthreads();
        int c = tid & 127, h = tid >> 7;
        float acc[4];
#pragma unroll
        for (int q = 0; q < 4; ++q) acc[q] = 0.f;
#pragma unroll 3
        for (int f4 = 0; f4 < 15; ++f4) {
            float4 wq = *(const float4*)&Wl[c * 60 + f4 * 4];
#pragma unroll
            for (int q = 0; q < 4; ++q) {
                float4 xq = *(const float4*)&xs[(h * 4 + q) * 60 + f4 * 4];
                acc[q] = fmaf(wq.x, xq.x, acc[q]);
                acc[q] = fmaf(wq.y, xq.y, acc[q]);
                acc[q] = fmaf(wq.z, xq.z, acc[q]);
                acc[q] = fmaf(wq.w, xq.w, acc[q]);
            }
        }
#pragma unroll
        for (int q = 0; q < 4; ++q) {
            int n = n0 + h * 4 + q;
            outp[(b * NN + n) * CC + c] = acc[q];
        }
    } else {
        __shared__ float S2s[CC];
        if (tid < CC) {
            int c = tid;
            float S1 = rsqrtf(pos_v[c] + EPSV) * pos_g[c];
            ws[WS_T1 + c] = (pos_b[c] - pos_m[c]) * S1 + pos_bb[c];
#pragma unroll
            for (int k = 0; k < 6; ++k) ws[WS_PWT + k * CC + c] = pos_w[c * 6 + k] * S1;
            float S2 = rsqrtf(attn_v[c] + EPSV) * attn_g[c];
            S2s[c] = S2;
            ws[WS_T2 + c] = (attn_b[c] - attn_m[c]) * S2 + attn_bb[c];
        }
        __syncthreads();
        uint32* wthp = (uint32*)ws + WS_WTH;
        for (int idx = tid; idx < 64 * CC; idx += 256) {
            int p = idx & 63, d = idx >> 6;
            float s = S2s[d];
            float2 w2 = *(const float2*)&attn_w[d * CC + 2 * p];
            h2 hv;
            hv.x = (_Float16)(w2.x * s);
            hv.y = (_Float16)(w2.y * s);
            wthp[p * CC + d] = __builtin_bit_cast(uint32, hv);
        }
    }
}

// One block per (b, i). Compact valid j's, then tiles of 16 j:
// phase1: alpha (f16 -> LDS) streamed from LDS broadcasts (register-lean),
// u in 8 regs; phase2: fdot2 matmul, wt half2 from global (coalesced, L2-hot);
// phase3: streaming exp-sum. __launch_bounds__(256,6): VGPR<=~85 so >=6
// blocks/CU co-reside (grid supplies 8/CU) — latency hiding via occupancy.
__global__ __launch_bounds__(256, 6) void main_kernel(
    const float* __restrict__ pos, const float* __restrict__ nrm,
    const int* __restrict__ rptr, const float* __restrict__ ws,
    float* __restrict__ out)
{
    const float* v    = ws + WS_V;
    const float* asrc = ws + WS_ASRC;
    const float* adst = ws + WS_ADST;
    const float* pwt  = ws + WS_PWT;
    const float* T1   = ws + WS_T1;
    const float* T2   = ws + WS_T2;
    const uint32* wth = (const uint32*)ws + WS_WTH;

    int blk = blockIdx.x;
    int b = blk >> 8, i = blk & 255;
    int tid = threadIdx.x;

    __shared__ float relf[NN * 6];
    __shared__ int   jlist[NN];
    __shared__ int   wcnt[4];
    __shared__ int   cnt_s;
    __shared__ _Float16 alpha_h[16 * 136];  // [slot][c], 272 B rows (16B-aligned)
    __shared__ float sered[CC], ored[CC];

    int rv = rptr[0];
    float r2 = (float)(rv * rv);
    const float* pib = pos + (size_t)(b * NN + i) * 3;
    const float* nib = nrm + (size_t)(b * NN + i) * 3;
    float pix = pib[0], piy = pib[1], piz = pib[2];
    float nix = nib[0], niy = nib[1], niz = nib[2];
    {
        int j = tid;
        const float* pj = pos + (size_t)(b * NN + j) * 3;
        const float* nj = nrm + (size_t)(b * NN + j) * 3;
        float dx = pix - pj[0], dy = piy - pj[1], dz = piz - pj[2];
        float ex = nix - nj[0], ey = niy - nj[1], ez = niz - nj[2];
        float d2 = dx * dx + dy * dy + dz * dz;
        bool valid = (d2 <= r2);
        unsigned long long m = __ballot(valid);
        int w = tid >> 6, lane = tid & 63;
        if (lane == 0) wcnt[w] = __popcll(m);
        __syncthreads();
        int off = 0;
        for (int w2 = 0; w2 < w; ++w2) off += wcnt[w2];
        if (tid == 0) cnt_s = wcnt[0] + wcnt[1] + wcnt[2] + wcnt[3];
        int rank = __popcll(m & ((1ull << lane) - 1ull));
        if (valid) {
            int s = off + rank;
            jlist[s] = j;
            relf[s * 6 + 0] = dx; relf[s * 6 + 1] = dy; relf[s * 6 + 2] = dz;
            relf[s * 6 + 3] = ex; relf[s * 6 + 4] = ey; relf[s * 6 + 5] = ez;
        }
    }
    __syncthreads();
    int cnt = cnt_s;   // >= 1 (self-loop)

    int c    = tid & 127;
    int half = tid >> 7;   // wave-uniform

    float pw[6];
#pragma unroll
    for (int k = 0; k < 6; ++k) pw[k] = pwt[k * CC + c];
    float T1c    = T1[c];
    float T2d    = T2[c];
    float adst_c = adst[(b * NN + i) * CC + c];

    float se = 0.f, ov = 0.f;

    for (int base = 0; base < cnt; base += 16) {
        int tcnt = min(16, cnt - base);
        int myn  = tcnt - half * 8;   // how many of my 8 slots are valid
        float u_reg[8];
        // ---- phase 1: alpha -> LDS (f16), u -> regs (streamed, low VGPR) ----
#pragma unroll
        for (int q = 0; q < 8; ++q) {
            float aval = 0.f;
            u_reg[q] = 0.f;
            if (q < myn) {
                int js = base + half * 8 + q;
                int j  = jlist[js];
                const float2* rp = (const float2*)&relf[js * 6];
                float2 r0 = rp[0], r1 = rp[1], r2f = rp[2];
                float dsum = T1c;
                dsum = fmaf(pw[0], r0.x, dsum);
                dsum = fmaf(pw[1], r0.y, dsum);
                dsum = fmaf(pw[2], r1.x, dsum);
                dsum = fmaf(pw[3], r1.y, dsum);
                dsum = fmaf(pw[4], r2f.x, dsum);
                dsum = fmaf(pw[5], r2f.y, dsum);
                float delta = fmaxf(dsum, 0.f);
                aval = adst_c - asrc[(b * NN + j) * CC + c] + delta;
                u_reg[q] = v[(b * NN + j) * CC + c] + delta;
            }
            alpha_h[(half * 8 + q) * 136 + c] = (_Float16)aval;
        }
        __syncthreads();
        // ---- phase 2: scores = alpha @ wt (+T2) via v_dot2_f32_f16 ----
        if (myn > 0) {
            float acc[8];
#pragma unroll
            for (int q = 0; q < 8; ++q) acc[q] = T2d;
            const uint32* wp = wth + c;
#pragma unroll 4
            for (int co = 0; co < 16; ++co) {
                uint32 w0 = wp[(co * 4 + 0) * CC];
                uint32 w1 = wp[(co * 4 + 1) * CC];
                uint32 w2 = wp[(co * 4 + 2) * CC];
                uint32 w3 = wp[(co * 4 + 3) * CC];
                h2 h0 = as_h2(w0), h1 = as_h2(w1), hh2 = as_h2(w2), h3 = as_h2(w3);
#pragma unroll
                for (int q = 0; q < 8; ++q) {
                    uint4 av = *(const uint4*)&alpha_h[(half * 8 + q) * 136 + co * 8];
                    acc[q] = FDOT2(as_h2(av.x), h0, acc[q]);
                    acc[q] = FDOT2(as_h2(av.y), h1, acc[q]);
                    acc[q] = FDOT2(as_h2(av.z), hh2, acc[q]);
                    acc[q] = FDOT2(as_h2(av.w), h3, acc[q]);
                }
            }
            // ---- phase 3: streaming exp-sum (scores>=0, no max needed) ----
#pragma unroll
            for (int q = 0; q < 8; ++q) {
                if (q < myn) {
                    float s = fmaxf(acc[q], 0.f);
                    float e = __expf(s);
                    se += e;
                    ov += e * u_reg[q];
                }
            }
        }
        __syncthreads();
    }

    if (half == 1) { sered[c] = se; ored[c] = ov; }
    __syncthreads();
    if (half == 0) {
        float S = se + sered[c];
        float O = ov + ored[c];
        out[(size_t)(b * NN + i) * CC + c] = O / S;
    }
}

extern "C" void kernel_launch(void* const* d_in, const int* in_sizes, int n_in,
                              void* d_out, int out_size, void* d_ws, size_t ws_size,
                              hipStream_t stream) {
    const float* x      = (const float*)d_in[0];
    const float* pos    = (const float*)d_in[1];
    const float* normal = (const float*)d_in[2];
    const float* W_lin  = (const float*)d_in[3];
    const float* W_src  = (const float*)d_in[4];
    const float* W_dst  = (const float*)d_in[5];
    const float* pos_w  = (const float*)d_in[6];
    const float* pos_b  = (const float*)d_in[7];
    const float* pos_g  = (const float*)d_in[8];
    const float* pos_bb = (const float*)d_in[9];
    const float* pos_m  = (const float*)d_in[10];
    const float* pos_v  = (const float*)d_in[11];
    const float* attn_w = (const float*)d_in[12];
    const float* attn_b = (const float*)d_in[13];
    const float* attn_g = (const float*)d_in[14];
    const float* attn_bb= (const float*)d_in[15];
    const float* attn_m = (const float*)d_in[16];
    const float* attn_v = (const float*)d_in[17];
    const int*   rptr   = (const int*)d_in[18];
    float* ws  = (float*)d_ws;
    float* out = (float*)d_out;

    prep_kernel<<<dim3(769), dim3(256), 0, stream>>>(
        x, W_lin, W_src, W_dst, pos_w, pos_b, pos_g, pos_bb, pos_m, pos_v,
        attn_w, attn_b, attn_g, attn_bb, attn_m, attn_v, ws);
    main_kernel<<<dim3(2048), dim3(256), 0, stream>>>(pos, normal, rptr, ws, out);
}